// Round 21
// baseline (67.443 us; speedup 1.0000x reference)
//
#include <hip/hip_runtime.h>
#include <hip/hip_bf16.h>

#define NEGV (-10000.0f)
#define EPSV (1e-5f)
#define NINF (-3.4e38f)

typedef __attribute__((ext_vector_type(8))) short short8;
typedef __attribute__((ext_vector_type(4))) float floatx4;

constexpr int Bsz = 4096, Nv = 64, Hd = 128, DEPTH = 3, H2 = 64;
constexpr int ESTR = 72;   // enc row stride bf16: 144 B (b128-aligned rows)

struct alignas(8) BH4 { __hip_bfloat162 a, b; };

__device__ __forceinline__ unsigned short f2b(float f) {
    unsigned int u = __builtin_bit_cast(unsigned int, f);
    u += 0x7fffu + ((u >> 16) & 1u);          // RNE to bf16
    return (unsigned short)(u >> 16);
}

// 16-lane all-reduce sum on the VALU via DPP (no LDS pipe)
template <int CTRL>
__device__ __forceinline__ float dpp_add(float v) {
    int y = __builtin_amdgcn_update_dpp(0, __builtin_bit_cast(int, v), CTRL, 0xf, 0xf, true);
    return v + __builtin_bit_cast(float, y);
}
__device__ __forceinline__ float sum16(float v) {
    v = dpp_add<0xB1>(v);    // quad_perm [1,0,3,2]  (xor 1)
    v = dpp_add<0x4E>(v);    // quad_perm [2,3,0,1]  (xor 2)
    v = dpp_add<0x124>(v);   // row_ror:4
    v = dpp_add<0x128>(v);   // row_ror:8
    return v;
}

// top-2 with argmax-index tracking. Ties are exact-safe: tie => f2==f1 =>
// the downstream select is value-identical whichever index wins.
__device__ __forceinline__ void t2insIdx(float& t1, float& t2, unsigned& i1,
                                         float v, unsigned iv) {
    bool c = v > t1;
    float lo = fminf(t1, v);
    t1 = fmaxf(t1, v);
    i1 = c ? iv : i1;
    t2 = fmaxf(t2, lo);
}

// Pack W[l] (128x64 f32) into bf16 MFMA-fragment order WITH column permutation:
// fragment position (ct,lr) sources actual column 4*lr+ct, so D-lane lr owns
// 4 consecutive output columns across its 4 accumulators.
__global__ void prep_w(const float* __restrict__ Ws, unsigned short* __restrict__ wt) {
    int idx = blockIdx.x * 256 + threadIdx.x;
    if (idx < DEPTH * 8192) {
        int l = idx >> 13, o = idx & 8191;
        int j = o & 7, q = (o >> 3) & 63, hi = (o >> 9) & 3, kt = o >> 11;
        int k = kt * 32 + hi * 8 + j;
        int srccol = (q & 15) * 4 + (q >> 4);
        wt[idx] = f2b(Ws[l * 8192 + k * 64 + srccol]);
    }
}

// NO __launch_bounds__ (only proven spill-free policy: R15/R18); need ~108
// unified regs -> 128 HW quantum -> 4 waves/SIMD; LDS 13.7 KB is not binding.
// block = 128 threads (2 waves) = 1 polyline; wave w owns rows w*32..w*32+31
// as two 16-row strips rt=0,1 (same 2-chain ILP as the R17 2-poly layout).
__global__
void subgraph_kernel(const float* __restrict__ hidden, const int* __restrict__ lvn,
                     const unsigned short* __restrict__ wt,
                     const float* __restrict__ bsv, const float* __restrict__ lnw,
                     const float* __restrict__ lnb, float* __restrict__ out)
{
    __shared__ __hip_bfloat16 encs[64][ESTR];      // 9216 B
    __shared__ float fb[2][4][2][64];              // [w][hi][plane][col] 4096 B
    __shared__ float apk[64][2];                   // bf16-bits (F1,F2)    512 B
    __shared__ unsigned short aidx[64];            // argmax row per col   128 B
                                                   // total 13952 B

    const int t = threadIdx.x;                     // 0..127
    const int lane = t & 63, w = t >> 6;           // 2 waves
    const int b = blockIdx.x;
    const int lr = lane & 15, hi = lane >> 4;
    const int L = lvn[b];
    const unsigned myrow[2] = {(unsigned)(w * 32 + lr), (unsigned)(w * 32 + 16 + lr)};

    // pad-mask addend per (strip, reg): row = w*32 + rt*16 + hi*4 + reg
    float madd[2][4];
#pragma unroll
    for (int rt = 0; rt < 2; ++rt)
#pragma unroll
        for (int reg = 0; reg < 4; ++reg)
            madd[rt][reg] = ((w * 32 + rt * 16 + hi * 4 + reg) >= L) ? NEGV : 0.0f;

    const float4* ab = (const float4*)(hidden + (size_t)b * Nv * Hd);

#pragma unroll
    for (int l = 0; l < DEPTH; ++l) {
        const short8* wfrag = (const short8*)(wt + l * 8192);

        // ---- A fragments for both strips ----
        short8 af[2][4];
        if (l == 0) {
#pragma unroll
            for (int rt = 0; rt < 2; ++rt)
#pragma unroll
                for (int kt = 0; kt < 4; ++kt) {
                    int fi = (int)myrow[rt] * 32 + kt * 8 + hi * 2;
                    float4 f0 = ab[fi], f1 = ab[fi + 1];
                    union { short8 s; __hip_bfloat162 h[4]; } u;
                    u.h[0] = __float22bfloat162_rn(make_float2(f0.x, f0.y));
                    u.h[1] = __float22bfloat162_rn(make_float2(f0.z, f0.w));
                    u.h[2] = __float22bfloat162_rn(make_float2(f1.x, f1.y));
                    u.h[3] = __float22bfloat162_rn(make_float2(f1.z, f1.w));
                    af[rt][kt] = u.s;
                }
        } else {
            // enc half: wave-local LDS rows (this wave wrote rows w*32..+31)
#pragma unroll
            for (int rt = 0; rt < 2; ++rt) {
                af[rt][0] = *(const short8*)&encs[myrow[rt]][hi * 8];
                af[rt][1] = *(const short8*)&encs[myrow[rt]][32 + hi * 8];
            }
            // loo half: select pre-rounded F1/F2 by argmax-index compare;
            // apk/aidx loads shared across both strips.
#pragma unroll
            for (int kt = 2; kt < 4; ++kt) {
                int cbase = (kt - 2) * 32 + hi * 8;
                short8 ar = *(const short8*)&aidx[cbase];
                const float4* ap = (const float4*)&apk[0][0];
                int fbq = cbase >> 1;                // float4 = 2 cols
                float4 q0 = ap[fbq], q1 = ap[fbq + 1], q2 = ap[fbq + 2], q3 = ap[fbq + 3];
                unsigned pk1s[8] = {
                    __builtin_bit_cast(unsigned, q0.x), __builtin_bit_cast(unsigned, q0.z),
                    __builtin_bit_cast(unsigned, q1.x), __builtin_bit_cast(unsigned, q1.z),
                    __builtin_bit_cast(unsigned, q2.x), __builtin_bit_cast(unsigned, q2.z),
                    __builtin_bit_cast(unsigned, q3.x), __builtin_bit_cast(unsigned, q3.z)};
                unsigned pk2s[8] = {
                    __builtin_bit_cast(unsigned, q0.y), __builtin_bit_cast(unsigned, q0.w),
                    __builtin_bit_cast(unsigned, q1.y), __builtin_bit_cast(unsigned, q1.w),
                    __builtin_bit_cast(unsigned, q2.y), __builtin_bit_cast(unsigned, q2.w),
                    __builtin_bit_cast(unsigned, q3.y), __builtin_bit_cast(unsigned, q3.w)};
#pragma unroll
                for (int rt = 0; rt < 2; ++rt) {
                    union { short8 s; unsigned u[4]; } uu;
#pragma unroll
                    for (int j2 = 0; j2 < 4; ++j2) {
                        unsigned s0 = ((unsigned)(unsigned short)ar[2 * j2]     == myrow[rt])
                                      ? pk2s[2 * j2]     : pk1s[2 * j2];
                        unsigned s1 = ((unsigned)(unsigned short)ar[2 * j2 + 1] == myrow[rt])
                                      ? pk2s[2 * j2 + 1] : pk1s[2 * j2 + 1];
                        uu.u[j2] = __builtin_amdgcn_perm(s1, s0, 0x05040100u);
                    }
                    af[rt][kt] = uu.s;
                }
            }
        }

        // ---- MFMA: B-frag shared by both strips (2 independent acc chains) ----
        floatx4 acc[2][4];
#pragma unroll
        for (int rt = 0; rt < 2; ++rt)
#pragma unroll
            for (int ct = 0; ct < 4; ++ct) { floatx4 z = {0.f, 0.f, 0.f, 0.f}; acc[rt][ct] = z; }
#pragma unroll
        for (int kt = 0; kt < 4; ++kt)
#pragma unroll
            for (int ct = 0; ct < 4; ++ct) {
                short8 bf = wfrag[(kt * 4 + hi) * 64 + ct * 16 + lr];
                acc[0][ct] = __builtin_amdgcn_mfma_f32_16x16x32_bf16(af[0][kt], bf, acc[0][ct], 0, 0, 0);
                acc[1][ct] = __builtin_amdgcn_mfma_f32_16x16x32_bf16(af[1][kt], bf, acc[1][ct], 0, 0, 0);
            }

        // ---- bias + LayerNorm + ReLU (in place); DPP all-reduce; both strips ----
        float4 bias = *(const float4*)(bsv + l * H2 + 4 * lr);
        float4 gwv  = *(const float4*)(lnw + l * H2 + 4 * lr);
        float4 gbv  = *(const float4*)(lnb + l * H2 + 4 * lr);
#pragma unroll
        for (int rt = 0; rt < 2; ++rt)
#pragma unroll
            for (int reg = 0; reg < 4; ++reg) {
                float x0 = acc[rt][0][reg] + bias.x;
                float x1 = acc[rt][1][reg] + bias.y;
                float x2 = acc[rt][2][reg] + bias.z;
                float x3 = acc[rt][3][reg] + bias.w;
                float s = sum16((x0 + x1) + (x2 + x3));
                float q = sum16((x0 * x0 + x1 * x1) + (x2 * x2 + x3 * x3));
                float mu  = s * (1.0f / 64.0f);
                float var = fmaxf(q * (1.0f / 64.0f) - mu * mu, 0.0f);
                float rstd = rsqrtf(var + EPSV);
                acc[rt][0][reg] = fmaxf(gwv.x * (x0 - mu) * rstd + gbv.x, 0.0f);
                acc[rt][1][reg] = fmaxf(gwv.y * (x1 - mu) * rstd + gbv.y, 0.0f);
                acc[rt][2][reg] = fmaxf(gwv.z * (x2 - mu) * rstd + gbv.z, 0.0f);
                acc[rt][3][reg] = fmaxf(gwv.w * (x3 - mu) * rstd + gbv.w, 0.0f);
            }

        if (l < DEPTH - 1) {
            // ---- enc pack -> LDS; masked top2 over BOTH strips with index ----
            float t1v[4] = {NINF, NINF, NINF, NINF}, t2v[4] = {NINF, NINF, NINF, NINF};
            unsigned i1v[4] = {0, 0, 0, 0};
#pragma unroll
            for (int rt = 0; rt < 2; ++rt)
#pragma unroll
                for (int reg = 0; reg < 4; ++reg) {
                    BH4 we;
                    we.a = __float22bfloat162_rn(make_float2(acc[rt][0][reg], acc[rt][1][reg]));
                    we.b = __float22bfloat162_rn(make_float2(acc[rt][2][reg], acc[rt][3][reg]));
                    *(BH4*)&encs[w * 32 + rt * 16 + hi * 4 + reg][4 * lr] = we;
                    float mk = madd[rt][reg];
                    unsigned rowi = w * 32 + rt * 16 + hi * 4 + reg;
                    t2insIdx(t1v[0], t2v[0], i1v[0], acc[rt][0][reg] + mk, rowi);
                    t2insIdx(t1v[1], t2v[1], i1v[1], acc[rt][1][reg] + mk, rowi);
                    t2insIdx(t1v[2], t2v[2], i1v[2], acc[rt][2][reg] + mk, rowi);
                    t2insIdx(t1v[3], t2v[3], i1v[3], acc[rt][3][reg] + mk, rowi);
                }
            // idx packed into low 6 mantissa bits of t1 (perturbation ~2^-17
            // rel, erased by the bf16 rounding of F1/F2; ties exact).
            float4 w0, w1;
#pragma unroll
            for (int ct = 0; ct < 4; ++ct) {
                unsigned bits = (__builtin_bit_cast(unsigned, t1v[ct]) & ~63u) | i1v[ct];
                (&w0.x)[ct] = __builtin_bit_cast(float, bits);
                (&w1.x)[ct] = t2v[ct];
            }
            *(float4*)&fb[w][hi][0][4 * lr] = w0;
            *(float4*)&fb[w][hi][1][4 * lr] = w1;
            __syncthreads();                 // publish partials (2-wave barrier)

            // ---- merge-once: 64 threads, 1 column each, 8 partials ----
            if (t < 64) {
                int c = t;
                float m1 = NINF, m2 = NINF; unsigned a1 = 0;
#pragma unroll
                for (int ww = 0; ww < 2; ++ww)
#pragma unroll
                    for (int h = 0; h < 4; ++h) {
                        float o1 = fb[ww][h][0][c], o2 = fb[ww][h][1][c];
                        bool cg = o1 > m1;
                        float lo = fminf(m1, o1);
                        m1 = fmaxf(m1, o1);
                        a1 = cg ? (__builtin_bit_cast(unsigned, o1) & 63u) : a1;
                        m2 = fmaxf(fmaxf(m2, o2), lo);
                    }
                apk[c][0] = __builtin_bit_cast(float, (unsigned)f2b(fmaxf(m1, 0.0f)));
                apk[c][1] = __builtin_bit_cast(float, (unsigned)f2b(fmaxf(m2, 0.0f)));
                aidx[c] = (unsigned short)a1;
            }
            __syncthreads();                 // publish merged selects
        } else {
            // ---- FINAL layer: out_loo[c] = max(f1_c,0) EXACTLY; out_enc = max enc ----
            float t1v[4], em4[4];
#pragma unroll
            for (int ct = 0; ct < 4; ++ct) {
                float a0 = acc[0][ct][0], a1_ = acc[0][ct][1];
                float a2 = acc[0][ct][2], a3 = acc[0][ct][3];
                float b0 = acc[1][ct][0], b1 = acc[1][ct][1];
                float b2 = acc[1][ct][2], b3 = acc[1][ct][3];
                em4[ct] = fmaxf(fmaxf(fmaxf(a0, a1_), fmaxf(a2, a3)),
                                fmaxf(fmaxf(b0, b1), fmaxf(b2, b3)));
                t1v[ct] = fmaxf(
                    fmaxf(fmaxf(a0 + madd[0][0], a1_ + madd[0][1]),
                          fmaxf(a2 + madd[0][2], a3 + madd[0][3])),
                    fmaxf(fmaxf(b0 + madd[1][0], b1 + madd[1][1]),
                          fmaxf(b2 + madd[1][2], b3 + madd[1][3])));
            }
            *(float4*)&fb[w][hi][0][4 * lr] = make_float4(t1v[0], t1v[1], t1v[2], t1v[3]);
            *(float4*)&fb[w][hi][1][4 * lr] = make_float4(em4[0], em4[1], em4[2], em4[3]);
            __syncthreads();                 // publish partials

            if (t < 64) {
                int c = t;
                float mm = NINF, me = NINF;
#pragma unroll
                for (int ww = 0; ww < 2; ++ww)
#pragma unroll
                    for (int h = 0; h < 4; ++h) {
                        mm = fmaxf(mm, fb[ww][h][0][c]);
                        me = fmaxf(me, fb[ww][h][1][c]);
                    }
                out[(size_t)b * Hd + c]      = me;              // enc half
                out[(size_t)b * Hd + 64 + c] = fmaxf(mm, 0.0f); // loo half
            }
        }
    }
}

extern "C" void kernel_launch(void* const* d_in, const int* in_sizes, int n_in,
                              void* d_out, int out_size, void* d_ws, size_t ws_size,
                              hipStream_t stream) {
    const float* hidden = (const float*)d_in[0];
    const int*   lvn    = (const int*)d_in[1];
    const float* Ws     = (const float*)d_in[2];
    const float* bs     = (const float*)d_in[3];
    const float* lnwp   = (const float*)d_in[4];
    const float* lnbp   = (const float*)d_in[5];
    unsigned short* wt  = (unsigned short*)d_ws;   // 48 KB bf16 fragment-packed W
    float* outp = (float*)d_out;

    prep_w<<<(DEPTH * 8192 + 255) / 256, 256, 0, stream>>>(Ws, wt);
    subgraph_kernel<<<Bsz, 128, 0, stream>>>(hidden, lvn, wt, bs, lnwp, lnbp, outp);
}

// Round 22
// 56.211 us; speedup vs baseline: 1.1998x; 1.1998x over previous
//
#include <hip/hip_runtime.h>
#include <hip/hip_bf16.h>

#define NEGV (-10000.0f)
#define EPSV (1e-5f)
#define NINF (-3.4e38f)

typedef __attribute__((ext_vector_type(8))) short short8;
typedef __attribute__((ext_vector_type(4))) float floatx4;

constexpr int Bsz = 4096, Nv = 64, Hd = 128, DEPTH = 3, H2 = 64;
constexpr int ESTR = 72;   // enc row stride bf16: 144 B (b128-aligned rows)

struct alignas(8) BH4 { __hip_bfloat162 a, b; };

__device__ __forceinline__ unsigned short f2b(float f) {
    unsigned int u = __builtin_bit_cast(unsigned int, f);
    u += 0x7fffu + ((u >> 16) & 1u);          // RNE to bf16
    return (unsigned short)(u >> 16);
}

// 16-lane all-reduce sum on the VALU via DPP (no LDS pipe)
template <int CTRL>
__device__ __forceinline__ float dpp_add(float v) {
    int y = __builtin_amdgcn_update_dpp(0, __builtin_bit_cast(int, v), CTRL, 0xf, 0xf, true);
    return v + __builtin_bit_cast(float, y);
}
__device__ __forceinline__ float sum16(float v) {
    v = dpp_add<0xB1>(v);    // quad_perm [1,0,3,2]  (xor 1)
    v = dpp_add<0x4E>(v);    // quad_perm [2,3,0,1]  (xor 2)
    v = dpp_add<0x124>(v);   // row_ror:4
    v = dpp_add<0x128>(v);   // row_ror:8
    return v;
}

// top-2 with argmax-index tracking. Tie rows are safe with ANY index choice:
// tie => f2==f1 numerically => the select is value-identical (exact).
__device__ __forceinline__ void t2insIdx(float& t1, float& t2, unsigned& i1,
                                         float v, unsigned iv) {
    bool c = v > t1;
    float lo = fminf(t1, v);
    t1 = fmaxf(t1, v);
    i1 = c ? iv : i1;
    t2 = fmaxf(t2, lo);
}

// Pack W[l] (128x64 f32) into bf16 MFMA-fragment order WITH column permutation:
// fragment position (ct,lr) sources actual column 4*lr+ct, so D-lane lr owns
// 4 consecutive output columns across its 4 accumulators.
__global__ void prep_w(const float* __restrict__ Ws, unsigned short* __restrict__ wt) {
    int idx = blockIdx.x * 256 + threadIdx.x;
    if (idx < DEPTH * 8192) {
        int l = idx >> 13, o = idx & 8191;
        int j = o & 7, q = (o >> 3) & 63, hi = (o >> 9) & 3, kt = o >> 11;
        int k = kt * 32 + hi * 8 + j;
        int srccol = (q & 15) * 4 + (q >> 4);
        wt[idx] = f2b(Ws[l * 8192 + k * 64 + srccol]);
    }
}

// bounds=3 is the only spill-free cap measured for this structure.
__global__ __launch_bounds__(256, 3)
void subgraph_kernel(const float* __restrict__ hidden, const int* __restrict__ lvn,
                     const unsigned short* __restrict__ wt,
                     const float* __restrict__ bsv, const float* __restrict__ lnw,
                     const float* __restrict__ lnb, float* __restrict__ out)
{
    // block = 2 polylines, 4 waves; wave w owns rows w*16..w*16+15 of BOTH.
    __shared__ __hip_bfloat16 encs[2][4][16][ESTR];  // [poly][wave][row][col] 18432 B
    __shared__ float fbuf3[4][4][2][3][64];          // [w][hi][p][plane][col]  24576 B
    __shared__ float apk[2][64][2];                  // bf16-packed (F1,F2) u32s 1024 B
    __shared__ unsigned short aidx[2][64];           // argmax row per column     256 B

    const int t = threadIdx.x;
    const int lane = t & 63, wid = t >> 6;
    const int b0 = blockIdx.x * 2;
    const int lr = lane & 15, hi = lane >> 4;
    const int L0 = lvn[b0], L1 = lvn[b0 + 1];
    const unsigned myrow = wid * 16 + lr;            // this lane's A-row

    // hoisted pad-mask addend per (poly, reg): row = wid*16 + hi*4 + reg
    float madd[2][4];
#pragma unroll
    for (int p = 0; p < 2; ++p)
#pragma unroll
        for (int reg = 0; reg < 4; ++reg)
            madd[p][reg] = ((int)(wid * 16 + hi * 4 + reg) >= (p ? L1 : L0)) ? NEGV : 0.0f;

    const float4* ab0 = (const float4*)(hidden + (size_t)b0 * Nv * Hd);
    const float4* ab1 = ab0 + (Nv * Hd) / 4;

#pragma unroll
    for (int l = 0; l < DEPTH; ++l) {
        const short8* wfrag = (const short8*)(wt + l * 8192);

        // ---- A fragments for both polylines ----
        short8 af[2][4];
        if (l == 0) {
#pragma unroll
            for (int p = 0; p < 2; ++p) {
                const float4* ab = p ? ab1 : ab0;
#pragma unroll
                for (int kt = 0; kt < 4; ++kt) {
                    int fi = (int)myrow * 32 + kt * 8 + hi * 2;
                    float4 f0 = ab[fi], f1 = ab[fi + 1];
                    union { short8 s; __hip_bfloat162 h[4]; } u;
                    u.h[0] = __float22bfloat162_rn(make_float2(f0.x, f0.y));
                    u.h[1] = __float22bfloat162_rn(make_float2(f0.z, f0.w));
                    u.h[2] = __float22bfloat162_rn(make_float2(f1.x, f1.y));
                    u.h[3] = __float22bfloat162_rn(make_float2(f1.z, f1.w));
                    af[p][kt] = u.s;
                }
            }
        } else {
            // enc half: wave-local LDS rows
#pragma unroll
            for (int p = 0; p < 2; ++p) {
                af[p][0] = *(const short8*)&encs[p][wid][lr][hi * 8];
                af[p][1] = *(const short8*)&encs[p][wid][lr][32 + hi * 8];
            }
            // loo half: select pre-rounded F1/F2 by argmax-index compare.
            // loo[r][c] = (r==argrow_c) ? max(f2,0) : max(f1,0); the m+NEGV
            // clamp is dead (LN bound |enc| <= 63/8 << 1e4).
#pragma unroll
            for (int kt = 2; kt < 4; ++kt) {
                int cbase = (kt - 2) * 32 + hi * 8;
#pragma unroll
                for (int p = 0; p < 2; ++p) {
                    short8 ar = *(const short8*)&aidx[p][cbase];
                    const float4* ap = (const float4*)&apk[p][0][0];
                    int fb = cbase >> 1;                 // float4 = 2 cols
                    float4 q0 = ap[fb], q1 = ap[fb + 1], q2 = ap[fb + 2], q3 = ap[fb + 3];
                    unsigned pk1s[8] = {
                        __builtin_bit_cast(unsigned, q0.x), __builtin_bit_cast(unsigned, q0.z),
                        __builtin_bit_cast(unsigned, q1.x), __builtin_bit_cast(unsigned, q1.z),
                        __builtin_bit_cast(unsigned, q2.x), __builtin_bit_cast(unsigned, q2.z),
                        __builtin_bit_cast(unsigned, q3.x), __builtin_bit_cast(unsigned, q3.z)};
                    unsigned pk2s[8] = {
                        __builtin_bit_cast(unsigned, q0.y), __builtin_bit_cast(unsigned, q0.w),
                        __builtin_bit_cast(unsigned, q1.y), __builtin_bit_cast(unsigned, q1.w),
                        __builtin_bit_cast(unsigned, q2.y), __builtin_bit_cast(unsigned, q2.w),
                        __builtin_bit_cast(unsigned, q3.y), __builtin_bit_cast(unsigned, q3.w)};
                    union { short8 s; unsigned u[4]; } uu;
#pragma unroll
                    for (int j2 = 0; j2 < 4; ++j2) {
                        unsigned s0 = ((unsigned)(unsigned short)ar[2 * j2]     == myrow)
                                      ? pk2s[2 * j2]     : pk1s[2 * j2];
                        unsigned s1 = ((unsigned)(unsigned short)ar[2 * j2 + 1] == myrow)
                                      ? pk2s[2 * j2 + 1] : pk1s[2 * j2 + 1];
                        uu.u[j2] = __builtin_amdgcn_perm(s1, s0, 0x05040100u);
                    }
                    af[p][kt] = uu.s;
                }
            }
        }

        // ---- MFMA: B-frag shared by both polylines ----
        floatx4 acc[2][4];
#pragma unroll
        for (int p = 0; p < 2; ++p)
#pragma unroll
            for (int ct = 0; ct < 4; ++ct) { floatx4 z = {0.f, 0.f, 0.f, 0.f}; acc[p][ct] = z; }
#pragma unroll
        for (int kt = 0; kt < 4; ++kt)
#pragma unroll
            for (int ct = 0; ct < 4; ++ct) {
                short8 bf = wfrag[(kt * 4 + hi) * 64 + ct * 16 + lr];
                acc[0][ct] = __builtin_amdgcn_mfma_f32_16x16x32_bf16(af[0][kt], bf, acc[0][ct], 0, 0, 0);
                acc[1][ct] = __builtin_amdgcn_mfma_f32_16x16x32_bf16(af[1][kt], bf, acc[1][ct], 0, 0, 0);
            }

        // ---- bias + LayerNorm + ReLU (in place); DPP all-reduce; both polys ----
        float4 bias = *(const float4*)(bsv + l * H2 + 4 * lr);
        float4 gwv  = *(const float4*)(lnw + l * H2 + 4 * lr);
        float4 gbv  = *(const float4*)(lnb + l * H2 + 4 * lr);
#pragma unroll
        for (int p = 0; p < 2; ++p)
#pragma unroll
            for (int reg = 0; reg < 4; ++reg) {
                float x0 = acc[p][0][reg] + bias.x;
                float x1 = acc[p][1][reg] + bias.y;
                float x2 = acc[p][2][reg] + bias.z;
                float x3 = acc[p][3][reg] + bias.w;
                float s = sum16((x0 + x1) + (x2 + x3));
                float q = sum16((x0 * x0 + x1 * x1) + (x2 * x2 + x3 * x3));
                float mu  = s * (1.0f / 64.0f);
                float var = fmaxf(q * (1.0f / 64.0f) - mu * mu, 0.0f);
                float rstd = rsqrtf(var + EPSV);
                acc[p][0][reg] = fmaxf(gwv.x * (x0 - mu) * rstd + gbv.x, 0.0f);
                acc[p][1][reg] = fmaxf(gwv.y * (x1 - mu) * rstd + gbv.y, 0.0f);
                acc[p][2][reg] = fmaxf(gwv.z * (x2 - mu) * rstd + gbv.z, 0.0f);
                acc[p][3][reg] = fmaxf(gwv.w * (x3 - mu) * rstd + gbv.w, 0.0f);
            }

        if (l < DEPTH - 1) {
            // ---- enc pack -> wave-local LDS; f32 masked top2 WITH index ----
#pragma unroll
            for (int p = 0; p < 2; ++p) {
                float t1v[4] = {NINF, NINF, NINF, NINF}, t2v[4] = {NINF, NINF, NINF, NINF};
                unsigned i1v[4] = {0, 0, 0, 0};
#pragma unroll
                for (int reg = 0; reg < 4; ++reg) {
                    BH4 we;
                    we.a = __float22bfloat162_rn(make_float2(acc[p][0][reg], acc[p][1][reg]));
                    we.b = __float22bfloat162_rn(make_float2(acc[p][2][reg], acc[p][3][reg]));
                    *(BH4*)&encs[p][wid][hi * 4 + reg][4 * lr] = we;
                    float mk = madd[p][reg];
                    unsigned rowi = wid * 16 + hi * 4 + reg;
                    t2insIdx(t1v[0], t2v[0], i1v[0], acc[p][0][reg] + mk, rowi);
                    t2insIdx(t1v[1], t2v[1], i1v[1], acc[p][1][reg] + mk, rowi);
                    t2insIdx(t1v[2], t2v[2], i1v[2], acc[p][2][reg] + mk, rowi);
                    t2insIdx(t1v[3], t2v[3], i1v[3], acc[p][3][reg] + mk, rowi);
                }
                *(float4*)&fbuf3[wid][hi][p][0][4 * lr] = make_float4(t1v[0], t1v[1], t1v[2], t1v[3]);
                *(float4*)&fbuf3[wid][hi][p][1][4 * lr] = make_float4(t2v[0], t2v[1], t2v[2], t2v[3]);
                *(float4*)&fbuf3[wid][hi][p][2][4 * lr] = make_float4(
                    __builtin_bit_cast(float, i1v[0]), __builtin_bit_cast(float, i1v[1]),
                    __builtin_bit_cast(float, i1v[2]), __builtin_bit_cast(float, i1v[3]));
            }
            __syncthreads();                 // publish partials

            // ---- merge-once: 128 threads, 1 column each; pre-round F1/F2 ----
            if (t < 128) {
                int p = t >> 6, c = t & 63;
                float m1 = NINF, m2 = NINF; unsigned a1 = 0;
#pragma unroll
                for (int w = 0; w < 4; ++w)
#pragma unroll
                    for (int h = 0; h < 4; ++h) {
                        float o1 = fbuf3[w][h][p][0][c], o2 = fbuf3[w][h][p][1][c];
                        unsigned io = __builtin_bit_cast(unsigned, fbuf3[w][h][p][2][c]);
                        bool cg = o1 > m1;
                        float lo = fminf(m1, o1);
                        m1 = fmaxf(m1, o1);
                        a1 = cg ? io : a1;
                        m2 = fmaxf(fmaxf(m2, o2), lo);
                    }
                float F1 = fmaxf(m1, 0.0f), F2 = fmaxf(m2, 0.0f);
                apk[p][c][0] = __builtin_bit_cast(float, (unsigned)f2b(F1));
                apk[p][c][1] = __builtin_bit_cast(float, (unsigned)f2b(F2));
                aidx[p][c] = (unsigned short)a1;
            }
            __syncthreads();                 // publish merged selects
        } else {
            // ---- FINAL layer: out_loo[c] = max(f1_c,0) EXACTLY (>=1 non-argmax
            // row always; all-tie => f2==f1). out_enc[c] = unmasked enc max.
            // No per-row selects, no shuffles, no epilogue.
#pragma unroll
            for (int p = 0; p < 2; ++p) {
                float t1v[4], em4[4];
#pragma unroll
                for (int ct = 0; ct < 4; ++ct) {
                    float a = acc[p][ct][0], b = acc[p][ct][1];
                    float c2 = acc[p][ct][2], d = acc[p][ct][3];
                    em4[ct] = fmaxf(fmaxf(a, b), fmaxf(c2, d));
                    t1v[ct] = fmaxf(fmaxf(a + madd[p][0], b + madd[p][1]),
                                    fmaxf(c2 + madd[p][2], d + madd[p][3]));
                }
                *(float4*)&fbuf3[wid][hi][p][0][4 * lr] = make_float4(t1v[0], t1v[1], t1v[2], t1v[3]);
                *(float4*)&fbuf3[wid][hi][p][1][4 * lr] = make_float4(em4[0], em4[1], em4[2], em4[3]);
            }
            __syncthreads();                 // publish partials

            if (t < 128) {
                int p = t >> 6, c = t & 63;
                float mm = NINF, me = NINF;
#pragma unroll
                for (int w = 0; w < 4; ++w)
#pragma unroll
                    for (int h = 0; h < 4; ++h) {
                        mm = fmaxf(mm, fbuf3[w][h][p][0][c]);
                        me = fmaxf(me, fbuf3[w][h][p][1][c]);
                    }
                out[(size_t)(b0 + p) * Hd + c]      = me;             // enc half
                out[(size_t)(b0 + p) * Hd + 64 + c] = fmaxf(mm, 0.0f); // loo half
            }
        }
    }
}

extern "C" void kernel_launch(void* const* d_in, const int* in_sizes, int n_in,
                              void* d_out, int out_size, void* d_ws, size_t ws_size,
                              hipStream_t stream) {
    const float* hidden = (const float*)d_in[0];
    const int*   lvn    = (const int*)d_in[1];
    const float* Ws     = (const float*)d_in[2];
    const float* bs     = (const float*)d_in[3];
    const float* lnwp   = (const float*)d_in[4];
    const float* lnbp   = (const float*)d_in[5];
    unsigned short* wt  = (unsigned short*)d_ws;   // 48 KB bf16 fragment-packed W
    float* outp = (float*)d_out;

    prep_w<<<(DEPTH * 8192 + 255) / 256, 256, 0, stream>>>(Ws, wt);
    subgraph_kernel<<<Bsz / 2, 256, 0, stream>>>(hidden, lvn, wt, bs, lnwp, lnbp, outp);
}